// Round 4
// baseline (38848.981 us; speedup 1.0000x reference)
//
#include <hip/hip_runtime.h>
#include <math.h>

// EarthMoverDistance: exact Hungarian (JV successive shortest path) with the
// FULL JV initialization: column reduction -> greedy matching -> reduction
// transfer -> augmenting row reduction (auction pass) -> exact SSP.
// B=8, N=1024, 3-D Euclidean cost. One wave per batch; lane owns 16 columns
// (c = lane*16+k) in registers. Cost matrix cached in d_ws (4 MB/batch).
// Deferred dual updates in SSP (validated rounds 1-3, absmax 0.0).
// All cross-lane reductions use a lexicographic (value, packed-index) total
// order so every lane computes bit-identical winners.

#define N     1024
#define BATCH 8
#define NSLOT 16          // columns per lane
#define INFV  1e9f
#define QCAP  4096
#define STEPMAX (6 * N)

__global__ void emd_zero_kernel(float* out) { out[0] = 0.0f; }

// ---- cost cache: D[b][r][c] = dist(S1[b][r], S2[b][c]) ----
__global__ __launch_bounds__(256)
void emd_dist_kernel(const float* __restrict__ S1, const float* __restrict__ S2,
                     float* __restrict__ D) {
    int b = blockIdx.x >> 10;
    int r = blockIdx.x & (N - 1);
    const float* s1 = S1 + ((size_t)b * N + r) * 3;
    float x1 = s1[0], y1 = s1[1], z1 = s1[2];
    const float* s2 = S2 + (size_t)b * N * 3;
    float* drow = D + ((size_t)b * N + r) * (size_t)N;
    for (int c = threadIdx.x; c < N; c += 256) {
        float dx = x1 - s2[3 * c], dy = y1 - s2[3 * c + 1], dz = z1 - s2[3 * c + 2];
        drow[c] = sqrtf(dx * dx + dy * dy + dz * dz);
    }
}

// ---- column reduction: v[c] = min_r D[r][c], imin[c] = argmin (first) ----
__global__ __launch_bounds__(256)
void emd_colmin_kernel(const float* __restrict__ D, float* __restrict__ V,
                       int* __restrict__ I) {
    int b = blockIdx.x >> 2;
    int c = ((blockIdx.x & 3) << 8) + threadIdx.x;
    const float* Db = D + ((size_t)b << 20);
    float best = INFV; int bi = 1;
    for (int r = 0; r < N; ++r) {
        float d = Db[(size_t)r * N + c];
        if (d < best) { best = d; bi = r + 1; }
    }
    V[b * N + c] = best;
    I[b * N + c] = bi;
}

template<int CTRL>
__device__ __forceinline__ float dppmin(float x) {
    int xi = __float_as_int(x);
    int yi = __builtin_amdgcn_update_dpp(xi, xi, CTRL, 0xF, 0xF, false);
    return fminf(x, __int_as_float(yi));
}

__device__ __forceinline__ float wave_min_f32(float x) {
    x = dppmin<0x111>(x);   // row_shr:1
    x = dppmin<0x112>(x);   // row_shr:2
    x = dppmin<0x114>(x);   // row_shr:4
    x = dppmin<0x118>(x);   // row_shr:8
    x = dppmin<0x142>(x);   // row_bcast:15
    x = dppmin<0x143>(x);   // row_bcast:31 -> lane 63 has global min
    return __int_as_float(__builtin_amdgcn_readlane(__float_as_int(x), 63));
}

template<bool CACHED>
__global__ __launch_bounds__(64, 1)
void emd_jv_kernel(const float* __restrict__ S1,
                   const float* __restrict__ S2,
                   const float* __restrict__ Dc,
                   const float* __restrict__ Vin,
                   const int*   __restrict__ Iin,
                   float* __restrict__ out) {
    __shared__ float4 s1u[N + 1];     // fallback path only (dead when CACHED)
    __shared__ float  u_lds[N + 1];   // row potentials
    __shared__ float  dentry[N + 1];  // D value when column settled (SSP)
    __shared__ int    rowm[N + 1];    // row -> matched col (0 = free)
    __shared__ int    q[QCAP];        // aug-row-reduction work queue
    __shared__ int    qcnt;

    const int lane = threadIdx.x;
    const int b = blockIdx.x;
    const float* s1g = S1 + (size_t)b * N * 3;
    const float* s2g = S2 + (size_t)b * N * 3;
    const float* Db = CACHED ? (Dc + ((size_t)b << 20)) : (const float*)0;
    const float NANF = __int_as_float(0x7fc00000);

    for (int t = lane; t < N; t += 64) {
        if (!CACHED)
            s1u[t + 1] = make_float4(s1g[3 * t], s1g[3 * t + 1], s1g[3 * t + 2], 0.0f);
        u_lds[t + 1] = 0.0f;
        rowm[t + 1] = 0;
    }
    if (lane == 0) { u_lds[0] = 0.0f; rowm[0] = 0; qcnt = 0; }

    // ---- per-lane column state: col j = c+1, c = lane*16+k ----
    float v[NSLOT];       // column potentials
    int   pr[NSLOT];      // matched row (0 = free)
    int   jpk[NSLOT];     // packed (pr<<11)|j
    int   imin[NSLOT];
    float x2[NSLOT], y2[NSLOT], z2[NSLOT];   // fallback only

    if (CACHED) {
#pragma unroll
        for (int k = 0; k < NSLOT; ++k) {
            int c = lane * NSLOT + k;
            v[k] = Vin[b * N + c];
            imin[k] = Iin[b * N + c];
        }
    } else {
#pragma unroll
        for (int k = 0; k < NSLOT; ++k) {
            int pt = lane * NSLOT + k;
            x2[k] = s2g[3 * pt + 0];
            y2[k] = s2g[3 * pt + 1];
            z2[k] = s2g[3 * pt + 2];
            v[k] = INFV; imin[k] = 1;
        }
    }
    __syncthreads();

    if (!CACHED) {
        for (int r = 1; r <= N; ++r) {
            float4 qq = s1u[r];
#pragma unroll
            for (int k = 0; k < NSLOT; ++k) {
                float dx = qq.x - x2[k], dy = qq.y - y2[k], dz = qq.z - z2[k];
                float d2 = dx * dx + dy * dy + dz * dz;
                bool upd = d2 < v[k];
                v[k] = upd ? d2 : v[k];
                imin[k] = upd ? r : imin[k];
            }
        }
#pragma unroll
        for (int k = 0; k < NSLOT; ++k) v[k] = sqrtf(v[k]);
    }

    // ---- greedy matching on tight edges ----
#pragma unroll
    for (int k = 0; k < NSLOT; ++k) {
        int j = lane * NSLOT + k + 1;
        int r = imin[k];
        int old = atomicCAS(&rowm[r], 0, j);
        pr[k] = (old == 0) ? r : 0;
        jpk[k] = (pr[k] << 11) | j;
    }
    __syncthreads();

    // lexicographic total order on (value, packed index): all lanes agree
    auto lt = [](float va, int ja, float vb, int jb) {
        return va < vb || (va == vb && ja < jb);
    };

    // min + second-min of (cost(r,.) - v) over all 1024 columns, with packed
    // (pr<<11)|j identities; identical result in every lane.
    auto scan2 = [&](int r, float& m1, int& jp1, float& m2, int& jp2) {
        const float4* dr4 = (const float4*)(Db + (size_t)(r - 1) * N);
        float4 qa = dr4[lane * 4 + 0];
        float4 qb = dr4[lane * 4 + 1];
        float4 qc = dr4[lane * 4 + 2];
        float4 qd = dr4[lane * 4 + 3];
        float dvv[NSLOT] = {qa.x, qa.y, qa.z, qa.w, qb.x, qb.y, qb.z, qb.w,
                            qc.x, qc.y, qc.z, qc.w, qd.x, qd.y, qd.z, qd.w};
        m1 = INFV; m2 = INFV; jp1 = 0x7FFFFFFF; jp2 = 0x7FFFFFFF;
#pragma unroll
        for (int k = 0; k < NSLOT; ++k) {
            float h = dvv[k] - v[k];
            int jj = jpk[k];
            if (lt(h, jj, m1, jp1)) { m2 = m1; jp2 = jp1; m1 = h; jp1 = jj; }
            else if (lt(h, jj, m2, jp2)) { m2 = h; jp2 = jj; }
        }
#pragma unroll
        for (int off = 32; off >= 1; off >>= 1) {
            float o1 = __shfl_xor(m1, off); int oj1 = __shfl_xor(jp1, off);
            float o2 = __shfl_xor(m2, off); int oj2 = __shfl_xor(jp2, off);
            if (lt(o1, oj1, m1, jp1)) {
                if (lt(m1, jp1, o2, oj2)) { m2 = m1; jp2 = jp1; }
                else { m2 = o2; jp2 = oj2; }
                m1 = o1; jp1 = oj1;
            } else if (lt(o1, oj1, m2, jp2)) { m2 = o1; jp2 = oj1; }
        }
    };

    if (CACHED) {
        // ---- reduction transfer (matched rows) ----
        for (int i = 1; i <= N; ++i) {
            int j1 = rowm[i];
            if (j1 == 0) continue;
            float m1, m2; int jp1, jp2;
            scan2(i, m1, jp1, m2, jp2);
            float min2x = ((jp1 & 0x7FF) == j1) ? m2 : m1;  // min over j != j1
            int cc = j1 - 1, lo = cc >> 4, kk = cc & 15;
            if (lane == lo) {
#pragma unroll
                for (int k = 0; k < NSLOT; ++k) if (k == kk) v[k] -= min2x;
            }
            if (lane == 0) u_lds[i] = min2x;
        }
        __syncthreads();

        // ---- augmenting row reduction (free rows, auction pass) ----
        for (int t = lane + 1; t <= N; t += 64)
            if (rowm[t] == 0) { int idx = atomicAdd(&qcnt, 1); q[idx] = t; }
        __syncthreads();
        int qtail = qcnt;       // wave-uniform
        int qhead = 0;
        int steps = 0;
        bool bail = false;
        while (qhead < qtail && !bail) {
            int i = q[qhead++];            // broadcast LDS read
            for (;;) {
                if (++steps > STEPMAX) { bail = true; break; }
                float m1, m2; int jp1, jp2;
                scan2(i, m1, jp1, m2, jp2);
                int j1 = jp1 & 0x7FF, i0 = jp1 >> 11;
                bool dec = (m1 < m2);
                if (!dec && i0 != 0) { j1 = jp2 & 0x7FF; i0 = jp2 >> 11; }
                int cc = j1 - 1, lo = cc >> 4, kk = cc & 15;
                float dv = m2 - m1;
                if (lane == lo) {
#pragma unroll
                    for (int k = 0; k < NSLOT; ++k) if (k == kk) {
                        if (dec) v[k] -= dv;
                        pr[k] = i; jpk[k] = (i << 11) | j1;
                    }
                }
                if (lane == 0) {
                    u_lds[i] = m2;
                    rowm[i] = j1;
                    if (i0) rowm[i0] = 0;
                    if (i0 && !dec && qtail < QCAP) q[qtail] = i0;
                }
                if (i0 == 0) break;
                if (!dec) { if (qtail < QCAP) qtail++; break; }
                i = i0;                    // v decreased: chain immediately
            }
        }
        __syncthreads();
    }

    float minv[NSLOT];
    int   way[NSLOT];

    auto expand = [&](int r, int jpred, float Dh) {
        if (CACHED) {
            const float4* dr4 = (const float4*)(Db + (size_t)(r - 1) * N);
            float4 qa = dr4[lane * 4 + 0];
            float4 qb = dr4[lane * 4 + 1];
            float4 qc = dr4[lane * 4 + 2];
            float4 qd = dr4[lane * 4 + 3];
            float base = Dh - u_lds[r];
            float dvv[NSLOT] = {qa.x, qa.y, qa.z, qa.w, qb.x, qb.y, qb.z, qb.w,
                                qc.x, qc.y, qc.z, qc.w, qd.x, qd.y, qd.z, qd.w};
#pragma unroll
            for (int k = 0; k < NSLOT; ++k) {
                float curabs = (dvv[k] - v[k]) + base;
                bool upd = curabs < minv[k];     // false for NaN (settled)
                minv[k] = upd ? curabs : minv[k];
                way[k] = upd ? jpred : way[k];
            }
        } else {
            float4 qq = s1u[r];
            float base = Dh - u_lds[r];
#pragma unroll
            for (int k = 0; k < NSLOT; ++k) {
                float dx = qq.x - x2[k], dy = qq.y - y2[k], dz = qq.z - z2[k];
                float d = sqrtf(dx * dx + dy * dy + dz * dz);
                float curabs = (d - v[k]) + base;
                bool upd = curabs < minv[k];
                minv[k] = upd ? curabs : minv[k];
                way[k] = upd ? jpred : way[k];
            }
        }
    };

    // ---- successive shortest paths for remaining free rows (exact) ----
    for (int i = 1; i <= N; ++i) {
        if (rowm[i] != 0) continue;

#pragma unroll
        for (int k = 0; k < NSLOT; ++k) { minv[k] = INFV; way[k] = 0; }
        unsigned used = 0u;
        float DT = 0.0f;
        int freecol = 0;

        expand(i, 0, 0.0f);

        int guard = 0;
        for (;;) {
            if (++guard > N + 4) break;
            float bestv = INFV; int bestjp = 0;
#pragma unroll
            for (int k = 0; k < NSLOT; ++k) {
                bool t = minv[k] < bestv;        // NaN-safe skip of settled
                bestv = t ? minv[k] : bestv;
                bestjp = t ? jpk[k] : bestjp;
            }
            float gmin = wave_min_f32(bestv);
            if (!(gmin < INFV * 0.5f)) break;
            unsigned long long tm = __ballot(bestv == gmin);
            DT = gmin;
            freecol = 0;
            while (tm) {
                int l = __ffsll((long long)tm) - 1;
                tm &= tm - 1;
                int jp = __builtin_amdgcn_readlane(bestjp, l);
                int jj = jp & 0x7FF;
                int rr = jp >> 11;
                if (rr == 0) { freecol = jj; break; }
                {
                    int cc = jj - 1;
                    int lo = cc >> 4, kk = cc & 15;
                    if (lane == 0) dentry[jj] = gmin;
                    bool mine = (lane == lo);
#pragma unroll
                    for (int k = 0; k < NSLOT; ++k)
                        if (k == kk) {
                            if (mine) { minv[k] = NANF; used |= (1u << k); }
                        }
                }
                expand(rr, jj, gmin);
            }
            if (freecol) break;
        }
        if (freecol == 0) continue;

        // deferred dual updates (pre-augment pr)
        if (lane == 0) u_lds[i] += DT;
#pragma unroll
        for (int k = 0; k < NSLOT; ++k) {
            if ((used >> k) & 1u) {
                int j = lane * NSLOT + k + 1;
                float dd = DT - dentry[j];
                v[k] -= dd;
                u_lds[pr[k]] += dd;      // distinct rows: race-free
            }
        }
        __syncthreads();

        // augment along alternating path (register p via readlanes)
        int j0 = freecol;
        int aguard = 0;
        while (j0 != 0) {
            if (++aguard > N + 4) break;
            int cc = j0 - 1;
            int lo = cc >> 4, kk = cc & 15;
            int wloc = way[0];
#pragma unroll
            for (int k = 1; k < NSLOT; ++k) if (k == kk) wloc = way[k];
            int j1 = __builtin_amdgcn_readlane(wloc, lo);
            int np;
            if (j1 == 0) np = i;
            else {
                int c1 = j1 - 1;
                int lo1 = c1 >> 4, kk1 = c1 & 15;
                int ploc = pr[0];
#pragma unroll
                for (int k = 1; k < NSLOT; ++k) if (k == kk1) ploc = pr[k];
                np = __builtin_amdgcn_readlane(ploc, lo1);
            }
            bool mine = (lane == lo);
#pragma unroll
            for (int k = 0; k < NSLOT; ++k)
                if (k == kk) {
                    if (mine) { pr[k] = np; jpk[k] = (np << 11) | j0; }
                }
            if (lane == 0) rowm[np] = j0;
            j0 = j1;
        }
        __syncthreads();
    }

    // ---- total matched cost ----
    float sum = 0.0f;
#pragma unroll
    for (int k = 0; k < NSLOT; ++k) {
        int c = lane * NSLOT + k;
        int r = pr[k] > 0 ? pr[k] : 1;
        if (CACHED) {
            sum += Db[(size_t)(r - 1) * N + c];
        } else {
            float4 qq = s1u[r];
            float dx = qq.x - x2[k], dy = qq.y - y2[k], dz = qq.z - z2[k];
            sum += sqrtf(dx * dx + dy * dy + dz * dz);
        }
    }
#pragma unroll
    for (int off = 32; off >= 1; off >>= 1) sum += __shfl_xor(sum, off);
    if (lane == 0) atomicAdd(out, sum * (1.0f / ((float)N * (float)BATCH)));
}

extern "C" void kernel_launch(void* const* d_in, const int* in_sizes, int n_in,
                              void* d_out, int out_size, void* d_ws, size_t ws_size,
                              hipStream_t stream) {
    const float* S1 = (const float*)d_in[0];
    const float* S2 = (const float*)d_in[1];
    float* out = (float*)d_out;

    size_t needD = (size_t)BATCH * N * N * sizeof(float);
    size_t needT = needD + (size_t)BATCH * N * (sizeof(float) + sizeof(int));

    emd_zero_kernel<<<1, 1, 0, stream>>>(out);

    if (ws_size >= needT) {
        float* D = (float*)d_ws;
        float* V = (float*)((char*)d_ws + needD);
        int*   I = (int*)(V + BATCH * N);
        emd_dist_kernel<<<BATCH * N, 256, 0, stream>>>(S1, S2, D);
        emd_colmin_kernel<<<BATCH * 4, 256, 0, stream>>>(D, V, I);
        emd_jv_kernel<true><<<BATCH, 64, 0, stream>>>(S1, S2, D, V, I, out);
    } else {
        emd_jv_kernel<false><<<BATCH, 64, 0, stream>>>(S1, S2, nullptr, nullptr, nullptr, out);
    }
}

// Round 5
// 26284.875 us; speedup vs baseline: 1.4780x; 1.4780x over previous
//
#include <hip/hip_runtime.h>
#include <math.h>

// EarthMoverDistance: exact Hungarian (JV successive shortest path).
// B=8, N=1024, 3-D Euclidean cost. One wave per batch; lane owns 16 columns
// (c = lane*16+k) in registers. Cost matrix cached in d_ws (4 MB/batch).
// R5: reverted the R4 JV-init (reduction transfer + auction regressed:
// FETCH unchanged => SSP work unchanged, init cost ~+15 ms). Added a 2-deep
// software pipeline over each round's tie list: tie n+1's cost row (HBM,
// ~900 cyc miss) is issued before tie n's slack update, overlapping the
// serialized misses that dominate R3's runtime.
// Deferred dual updates in SSP (validated rounds 1-4, absmax 0.0).

#define N     1024
#define BATCH 8
#define NSLOT 16          // columns per lane
#define INFV  1e9f

__global__ void emd_zero_kernel(float* out) { out[0] = 0.0f; }

// ---- cost cache: D[b][r][c] = dist(S1[b][r], S2[b][c]) ----
__global__ __launch_bounds__(256)
void emd_dist_kernel(const float* __restrict__ S1, const float* __restrict__ S2,
                     float* __restrict__ D) {
    int b = blockIdx.x >> 10;
    int r = blockIdx.x & (N - 1);
    const float* s1 = S1 + ((size_t)b * N + r) * 3;
    float x1 = s1[0], y1 = s1[1], z1 = s1[2];
    const float* s2 = S2 + (size_t)b * N * 3;
    float* drow = D + ((size_t)b * N + r) * (size_t)N;
    for (int c = threadIdx.x; c < N; c += 256) {
        float dx = x1 - s2[3 * c], dy = y1 - s2[3 * c + 1], dz = z1 - s2[3 * c + 2];
        drow[c] = sqrtf(dx * dx + dy * dy + dz * dz);
    }
}

// ---- column reduction: v[c] = min_r D[r][c], imin[c] = argmin (first) ----
__global__ __launch_bounds__(256)
void emd_colmin_kernel(const float* __restrict__ D, float* __restrict__ V,
                       int* __restrict__ I) {
    int b = blockIdx.x >> 2;
    int c = ((blockIdx.x & 3) << 8) + threadIdx.x;
    const float* Db = D + ((size_t)b << 20);
    float best = INFV; int bi = 1;
    for (int r = 0; r < N; ++r) {
        float d = Db[(size_t)r * N + c];
        if (d < best) { best = d; bi = r + 1; }
    }
    V[b * N + c] = best;
    I[b * N + c] = bi;
}

template<int CTRL>
__device__ __forceinline__ float dppmin(float x) {
    int xi = __float_as_int(x);
    int yi = __builtin_amdgcn_update_dpp(xi, xi, CTRL, 0xF, 0xF, false);
    return fminf(x, __int_as_float(yi));
}

__device__ __forceinline__ float wave_min_f32(float x) {
    x = dppmin<0x111>(x);   // row_shr:1
    x = dppmin<0x112>(x);   // row_shr:2
    x = dppmin<0x114>(x);   // row_shr:4
    x = dppmin<0x118>(x);   // row_shr:8
    x = dppmin<0x142>(x);   // row_bcast:15
    x = dppmin<0x143>(x);   // row_bcast:31 -> lane 63 has global min
    return __int_as_float(__builtin_amdgcn_readlane(__float_as_int(x), 63));
}

struct RowFrag { float4 a, b, c, d; float u; };

template<bool CACHED>
__global__ __launch_bounds__(64, 1)
void emd_jv_kernel(const float* __restrict__ S1,
                   const float* __restrict__ S2,
                   const float* __restrict__ Dc,
                   const float* __restrict__ Vin,
                   const int*   __restrict__ Iin,
                   float* __restrict__ out) {
    __shared__ float4 s1u[N + 1];     // fallback path only (dead when CACHED)
    __shared__ float  u_lds[N + 1];   // row potentials
    __shared__ float  dentry[N + 1];  // D value when column settled
    __shared__ int    rowm[N + 1];    // row -> matched col (0 = free)

    const int lane = threadIdx.x;
    const int b = blockIdx.x;
    const float* s1g = S1 + (size_t)b * N * 3;
    const float* s2g = S2 + (size_t)b * N * 3;
    const float* Db = CACHED ? (Dc + ((size_t)b << 20)) : (const float*)0;
    const float NANF = __int_as_float(0x7fc00000);

    for (int t = lane; t < N; t += 64) {
        if (!CACHED)
            s1u[t + 1] = make_float4(s1g[3 * t], s1g[3 * t + 1], s1g[3 * t + 2], 0.0f);
        u_lds[t + 1] = 0.0f;
        rowm[t + 1] = 0;
    }
    if (lane == 0) { u_lds[0] = 0.0f; rowm[0] = 0; }

    // ---- per-lane column state: col j = c+1, c = lane*16+k ----
    float v[NSLOT];       // column potentials
    int   pr[NSLOT];      // matched row (0 = free)
    int   jpk[NSLOT];     // packed (pr<<11)|j
    int   imin[NSLOT];
    float x2[NSLOT], y2[NSLOT], z2[NSLOT];   // fallback only

    if (CACHED) {
#pragma unroll
        for (int k = 0; k < NSLOT; ++k) {
            int c = lane * NSLOT + k;
            v[k] = Vin[b * N + c];
            imin[k] = Iin[b * N + c];
        }
    } else {
#pragma unroll
        for (int k = 0; k < NSLOT; ++k) {
            int pt = lane * NSLOT + k;
            x2[k] = s2g[3 * pt + 0];
            y2[k] = s2g[3 * pt + 1];
            z2[k] = s2g[3 * pt + 2];
            v[k] = INFV; imin[k] = 1;
        }
    }
    __syncthreads();

    if (!CACHED) {
        for (int r = 1; r <= N; ++r) {
            float4 qq = s1u[r];
#pragma unroll
            for (int k = 0; k < NSLOT; ++k) {
                float dx = qq.x - x2[k], dy = qq.y - y2[k], dz = qq.z - z2[k];
                float d2 = dx * dx + dy * dy + dz * dz;
                bool upd = d2 < v[k];
                v[k] = upd ? d2 : v[k];
                imin[k] = upd ? r : imin[k];
            }
        }
#pragma unroll
        for (int k = 0; k < NSLOT; ++k) v[k] = sqrtf(v[k]);
    }

    // ---- greedy matching on tight edges ----
#pragma unroll
    for (int k = 0; k < NSLOT; ++k) {
        int j = lane * NSLOT + k + 1;
        int r = imin[k];
        int old = atomicCAS(&rowm[r], 0, j);
        pr[k] = (old == 0) ? r : 0;
        jpk[k] = (pr[k] << 11) | j;
    }
    __syncthreads();

    float minv[NSLOT];
    int   way[NSLOT];

    // issue row-r loads (cost row fragment + u[r]); apply waits only on these
    auto loadrow = [&](int r) -> RowFrag {
        RowFrag R;
        if (CACHED) {
            const float4* dr4 = (const float4*)(Db + (size_t)(r - 1) * N);
            R.a = dr4[lane * 4 + 0];
            R.b = dr4[lane * 4 + 1];
            R.c = dr4[lane * 4 + 2];
            R.d = dr4[lane * 4 + 3];
        } else {
            R.a = s1u[r];                 // {x,y,z,-}
        }
        R.u = u_lds[r];
        return R;
    };

    auto applyRow = [&](const RowFrag& R, int jpred, float Dh) {
        float base = Dh - R.u;
        if (CACHED) {
            float dvv[NSLOT] = {R.a.x, R.a.y, R.a.z, R.a.w, R.b.x, R.b.y, R.b.z, R.b.w,
                                R.c.x, R.c.y, R.c.z, R.c.w, R.d.x, R.d.y, R.d.z, R.d.w};
#pragma unroll
            for (int k = 0; k < NSLOT; ++k) {
                float curabs = (dvv[k] - v[k]) + base;
                bool upd = curabs < minv[k];     // false for NaN (settled)
                minv[k] = upd ? curabs : minv[k];
                way[k] = upd ? jpred : way[k];
            }
        } else {
#pragma unroll
            for (int k = 0; k < NSLOT; ++k) {
                float dx = R.a.x - x2[k], dy = R.a.y - y2[k], dz = R.a.z - z2[k];
                float d = sqrtf(dx * dx + dy * dy + dz * dz);
                float curabs = (d - v[k]) + base;
                bool upd = curabs < minv[k];
                minv[k] = upd ? curabs : minv[k];
                way[k] = upd ? jpred : way[k];
            }
        }
    };

    // ---- successive shortest paths for free rows (exact) ----
    for (int i = 1; i <= N; ++i) {
        if (rowm[i] != 0) continue;

        unsigned used = 0u;
        float DT = 0.0f;
        int freecol = 0;

        RowFrag R0 = loadrow(i);          // prefetch: overlaps minv/way init
#pragma unroll
        for (int k = 0; k < NSLOT; ++k) { minv[k] = INFV; way[k] = 0; }
        applyRow(R0, 0, 0.0f);

        int guard = 0;
        for (;;) {
            if (++guard > N + 4) break;
            float bestv = INFV; int bestjp = 0;
#pragma unroll
            for (int k = 0; k < NSLOT; ++k) {
                bool t = minv[k] < bestv;        // NaN-safe skip of settled
                bestv = t ? minv[k] : bestv;
                bestjp = t ? jpk[k] : bestjp;
            }
            float gmin = wave_min_f32(bestv);
            if (!(gmin < INFV * 0.5f)) break;
            unsigned long long tm = __ballot(bestv == gmin);
            DT = gmin;
            freecol = 0;

            // pop next matched tie; set freecol and stop if a free column ties
            auto popTie = [&](int& jp) -> bool {
                while (tm) {
                    int l = __ffsll((long long)tm) - 1;
                    tm &= tm - 1;
                    int p = __builtin_amdgcn_readlane(bestjp, l);
                    if ((p >> 11) == 0) { freecol = p & 0x7FF; return false; }
                    jp = p; return true;
                }
                return false;
            };

            // 2-deep pipeline: issue tie n+1's row loads before applying tie n
            int jpC; bool have = popTie(jpC);
            if (have) {
                RowFrag RC = loadrow(jpC >> 11);
                for (;;) {
                    int jpN = 0;
                    bool haveN = (freecol == 0) ? popTie(jpN) : false;
                    RowFrag RN;
                    if (haveN) RN = loadrow(jpN >> 11);
                    // settle jpC's column: NaN + used + dentry
                    int jj = jpC & 0x7FF;
                    int cc = jj - 1, lo = cc >> 4, kk = cc & 15;
                    if (lane == 0) dentry[jj] = gmin;
                    bool mine = (lane == lo);
#pragma unroll
                    for (int k = 0; k < NSLOT; ++k)
                        if (k == kk) {
                            if (mine) { minv[k] = NANF; used |= (1u << k); }
                        }
                    applyRow(RC, jj, gmin);
                    if (!haveN) break;
                    jpC = jpN; RC = RN;
                }
            }
            if (freecol) break;
        }
        if (freecol == 0) continue;

        // deferred dual updates (pre-augment pr)
        if (lane == 0) u_lds[i] += DT;
#pragma unroll
        for (int k = 0; k < NSLOT; ++k) {
            if ((used >> k) & 1u) {
                int j = lane * NSLOT + k + 1;
                float dd = DT - dentry[j];
                v[k] -= dd;
                u_lds[pr[k]] += dd;      // distinct rows: race-free
            }
        }
        __syncthreads();

        // augment along alternating path (register p via readlanes)
        int j0 = freecol;
        int aguard = 0;
        while (j0 != 0) {
            if (++aguard > N + 4) break;
            int cc = j0 - 1;
            int lo = cc >> 4, kk = cc & 15;
            int wloc = way[0];
#pragma unroll
            for (int k = 1; k < NSLOT; ++k) if (k == kk) wloc = way[k];
            int j1 = __builtin_amdgcn_readlane(wloc, lo);
            int np;
            if (j1 == 0) np = i;
            else {
                int c1 = j1 - 1;
                int lo1 = c1 >> 4, kk1 = c1 & 15;
                int ploc = pr[0];
#pragma unroll
                for (int k = 1; k < NSLOT; ++k) if (k == kk1) ploc = pr[k];
                np = __builtin_amdgcn_readlane(ploc, lo1);
            }
            bool mine = (lane == lo);
#pragma unroll
            for (int k = 0; k < NSLOT; ++k)
                if (k == kk) {
                    if (mine) { pr[k] = np; jpk[k] = (np << 11) | j0; }
                }
            if (lane == 0) rowm[np] = j0;
            j0 = j1;
        }
        __syncthreads();
    }

    // ---- total matched cost ----
    float sum = 0.0f;
#pragma unroll
    for (int k = 0; k < NSLOT; ++k) {
        int c = lane * NSLOT + k;
        int r = pr[k] > 0 ? pr[k] : 1;
        if (CACHED) {
            sum += Db[(size_t)(r - 1) * N + c];
        } else {
            float4 qq = s1u[r];
            float dx = qq.x - x2[k], dy = qq.y - y2[k], dz = qq.z - z2[k];
            sum += sqrtf(dx * dx + dy * dy + dz * dz);
        }
    }
#pragma unroll
    for (int off = 32; off >= 1; off >>= 1) sum += __shfl_xor(sum, off);
    if (lane == 0) atomicAdd(out, sum * (1.0f / ((float)N * (float)BATCH)));
}

extern "C" void kernel_launch(void* const* d_in, const int* in_sizes, int n_in,
                              void* d_out, int out_size, void* d_ws, size_t ws_size,
                              hipStream_t stream) {
    const float* S1 = (const float*)d_in[0];
    const float* S2 = (const float*)d_in[1];
    float* out = (float*)d_out;

    size_t needD = (size_t)BATCH * N * N * sizeof(float);
    size_t needT = needD + (size_t)BATCH * N * (sizeof(float) + sizeof(int));

    emd_zero_kernel<<<1, 1, 0, stream>>>(out);

    if (ws_size >= needT) {
        float* D = (float*)d_ws;
        float* V = (float*)((char*)d_ws + needD);
        int*   I = (int*)(V + BATCH * N);
        emd_dist_kernel<<<BATCH * N, 256, 0, stream>>>(S1, S2, D);
        emd_colmin_kernel<<<BATCH * 4, 256, 0, stream>>>(D, V, I);
        emd_jv_kernel<true><<<BATCH, 64, 0, stream>>>(S1, S2, D, V, I, out);
    } else {
        emd_jv_kernel<false><<<BATCH, 64, 0, stream>>>(S1, S2, nullptr, nullptr, nullptr, out);
    }
}

// Round 6
// 22297.324 us; speedup vs baseline: 1.7423x; 1.1788x over previous
//
#include <hip/hip_runtime.h>
#include <hip/hip_fp16.h>
#include <math.h>

// EarthMoverDistance: exact Hungarian (JV successive shortest path).
// B=8, N=1024, 3-D Euclidean cost. One wave per batch; lane owns 16 columns
// (c = lane*16+k) in registers.
// R6 (base = R3 structure; R4 init and R5 pipeline both regressed, reverted):
//  - fp16 cost matrix in d_ws (2 MB/batch -> XCD-L2 resident; R3's 4 MB fp32
//    exactly matched the 4 MB L2 and paid LLC latency per settle). SSP is
//    exact on the rounded matrix; FINAL SUM recomputed in fp32 from coords,
//    so output error is only matching changes on near-ties (~1e-4 level).
//  - free-column-first tie scan: if a free column ties at gmin, terminate
//    with zero expands that round.
//  - per settle: issue cost-row + u[r] loads immediately after the winner
//    readlane; settle bookkeeping overlaps the load latency.
// Deferred dual updates (validated rounds 1-5, absmax 0.0).

#define N     1024
#define BATCH 8
#define NSLOT 16          // columns per lane
#define INFV  1e9f

__global__ void emd_zero_kernel(float* out) { out[0] = 0.0f; }

// ---- cost cache: D[b][r][c] = fp16(dist(S1[b][r], S2[b][c])) ----
__global__ __launch_bounds__(256)
void emd_dist_kernel(const float* __restrict__ S1, const float* __restrict__ S2,
                     __half* __restrict__ D) {
    int b = blockIdx.x >> 10;
    int r = blockIdx.x & (N - 1);
    const float* s1 = S1 + ((size_t)b * N + r) * 3;
    float x1 = s1[0], y1 = s1[1], z1 = s1[2];
    const float* s2 = S2 + (size_t)b * N * 3;
    __half* drow = D + ((size_t)b * N + r) * (size_t)N;
    for (int c = threadIdx.x; c < N; c += 256) {
        float dx = x1 - s2[3 * c], dy = y1 - s2[3 * c + 1], dz = z1 - s2[3 * c + 2];
        drow[c] = __float2half_rn(sqrtf(dx * dx + dy * dy + dz * dz));
    }
}

// ---- column reduction over the fp16 matrix: v[c] = min_r C'(r,c) ----
__global__ __launch_bounds__(256)
void emd_colmin_kernel(const __half* __restrict__ D, float* __restrict__ V,
                       int* __restrict__ I) {
    int b = blockIdx.x >> 2;
    int c = ((blockIdx.x & 3) << 8) + threadIdx.x;
    const __half* Db = D + ((size_t)b << 20);
    float best = INFV; int bi = 1;
    for (int r = 0; r < N; ++r) {
        float d = __half2float(Db[(size_t)r * N + c]);
        if (d < best) { best = d; bi = r + 1; }
    }
    V[b * N + c] = best;
    I[b * N + c] = bi;
}

template<int CTRL>
__device__ __forceinline__ float dppmin(float x) {
    int xi = __float_as_int(x);
    int yi = __builtin_amdgcn_update_dpp(xi, xi, CTRL, 0xF, 0xF, false);
    return fminf(x, __int_as_float(yi));
}

__device__ __forceinline__ float wave_min_f32(float x) {
    x = dppmin<0x111>(x);   // row_shr:1
    x = dppmin<0x112>(x);   // row_shr:2
    x = dppmin<0x114>(x);   // row_shr:4
    x = dppmin<0x118>(x);   // row_shr:8
    x = dppmin<0x142>(x);   // row_bcast:15
    x = dppmin<0x143>(x);   // row_bcast:31 -> lane 63 has global min
    return __int_as_float(__builtin_amdgcn_readlane(__float_as_int(x), 63));
}

struct Frag { uint4 w0, w1; float ur; float4 q; };

template<bool CACHED>
__global__ __launch_bounds__(64, 1)
void emd_jv_kernel(const float* __restrict__ S1,
                   const float* __restrict__ S2,
                   const __half* __restrict__ Dc,
                   const float* __restrict__ Vin,
                   const int*   __restrict__ Iin,
                   float* __restrict__ out) {
    __shared__ float4 s1u[N + 1];     // row coords (both modes; final fp32 sum)
    __shared__ float  u_lds[N + 1];   // row potentials
    __shared__ float  dentry[N + 1];  // D value when column settled
    __shared__ int    rowm[N + 1];    // row -> matched col (0 = free)

    const int lane = threadIdx.x;
    const int b = blockIdx.x;
    const float* s1g = S1 + (size_t)b * N * 3;
    const float* s2g = S2 + (size_t)b * N * 3;
    const __half* Db = CACHED ? (Dc + ((size_t)b << 20)) : (const __half*)0;
    const float NANF = __int_as_float(0x7fc00000);

    for (int t = lane; t < N; t += 64) {
        s1u[t + 1] = make_float4(s1g[3 * t], s1g[3 * t + 1], s1g[3 * t + 2], 0.0f);
        u_lds[t + 1] = 0.0f;
        rowm[t + 1] = 0;
    }
    if (lane == 0) { u_lds[0] = 0.0f; rowm[0] = 0; }

    // ---- per-lane column state: col j = c+1, c = lane*16+k ----
    float v[NSLOT];       // column potentials
    int   pr[NSLOT];      // matched row (0 = free)
    int   jpk[NSLOT];     // packed (pr<<11)|j
    int   imin[NSLOT];
    float x2[NSLOT], y2[NSLOT], z2[NSLOT];  // S2 coords (final fp32 sum)

#pragma unroll
    for (int k = 0; k < NSLOT; ++k) {
        int pt = lane * NSLOT + k;
        x2[k] = s2g[3 * pt + 0];
        y2[k] = s2g[3 * pt + 1];
        z2[k] = s2g[3 * pt + 2];
    }
    if (CACHED) {
#pragma unroll
        for (int k = 0; k < NSLOT; ++k) {
            int c = lane * NSLOT + k;
            v[k] = Vin[b * N + c];
            imin[k] = Iin[b * N + c];
        }
    } else {
#pragma unroll
        for (int k = 0; k < NSLOT; ++k) { v[k] = INFV; imin[k] = 1; }
    }
    __syncthreads();

    if (!CACHED) {
        for (int r = 1; r <= N; ++r) {
            float4 qq = s1u[r];
#pragma unroll
            for (int k = 0; k < NSLOT; ++k) {
                float dx = qq.x - x2[k], dy = qq.y - y2[k], dz = qq.z - z2[k];
                float d2 = dx * dx + dy * dy + dz * dz;
                bool upd = d2 < v[k];
                v[k] = upd ? d2 : v[k];
                imin[k] = upd ? r : imin[k];
            }
        }
#pragma unroll
        for (int k = 0; k < NSLOT; ++k) v[k] = sqrtf(v[k]);
    }

    // ---- greedy matching on tight edges ----
#pragma unroll
    for (int k = 0; k < NSLOT; ++k) {
        int j = lane * NSLOT + k + 1;
        int r = imin[k];
        int old = atomicCAS(&rowm[r], 0, j);
        pr[k] = (old == 0) ? r : 0;
        jpk[k] = (pr[k] << 11) | j;
    }
    __syncthreads();

    float minv[NSLOT];
    int   way[NSLOT];

    // issue row-r loads (cost-row fragment + u[r]); consumer waits only these
    auto issueLoads = [&](int rr) -> Frag {
        Frag F;
        if (CACHED) {
            const uint4* dr = (const uint4*)(Db + (size_t)(rr - 1) * N);
            F.w0 = dr[lane * 2 + 0];       // 8 halves
            F.w1 = dr[lane * 2 + 1];       // 8 halves
        } else {
            F.q = s1u[rr];
        }
        F.ur = u_lds[rr];
        return F;
    };

    auto applyFrag = [&](const Frag& F, int jpred, float Dh) {
        float base = Dh - F.ur;
        if (CACHED) {
            float h[NSLOT];
            const unsigned* w = (const unsigned*)&F.w0;   // w0,w1 contiguous
#pragma unroll
            for (int t = 0; t < 8; ++t) {
                unsigned word = w[t];
                __half2 hh = *reinterpret_cast<const __half2*>(&word);
                float2 f2 = __half22float2(hh);
                h[2 * t] = f2.x; h[2 * t + 1] = f2.y;
            }
#pragma unroll
            for (int k = 0; k < NSLOT; ++k) {
                float cur = (h[k] - v[k]) + base;
                bool upd = cur < minv[k];         // false for NaN (settled)
                minv[k] = upd ? cur : minv[k];
                way[k] = upd ? jpred : way[k];
            }
        } else {
#pragma unroll
            for (int k = 0; k < NSLOT; ++k) {
                float dx = F.q.x - x2[k], dy = F.q.y - y2[k], dz = F.q.z - z2[k];
                float d = sqrtf(dx * dx + dy * dy + dz * dz);
                float cur = (d - v[k]) + base;
                bool upd = cur < minv[k];
                minv[k] = upd ? cur : minv[k];
                way[k] = upd ? jpred : way[k];
            }
        }
    };

    // ---- successive shortest paths for free rows (exact on C') ----
    for (int i = 1; i <= N; ++i) {
        if (rowm[i] != 0) continue;

        unsigned used = 0u;
        float DT = 0.0f;
        int freecol = 0;

        Frag F0 = issueLoads(i);          // overlaps minv/way init
#pragma unroll
        for (int k = 0; k < NSLOT; ++k) { minv[k] = INFV; way[k] = 0; }
        applyFrag(F0, 0, 0.0f);

        int guard = 0;
        for (;;) {
            if (++guard > N + 4) break;
            float bestv = INFV; int bestjp = 0;
#pragma unroll
            for (int k = 0; k < NSLOT; ++k) {
                bool t = minv[k] < bestv;        // NaN-safe skip of settled
                bestv = t ? minv[k] : bestv;
                bestjp = t ? jpk[k] : bestjp;
            }
            float gmin = wave_min_f32(bestv);
            if (!(gmin < INFV * 0.5f)) break;
            unsigned long long tm = __ballot(bestv == gmin);
            DT = gmin;
            freecol = 0;

            // 1) free-column short-circuit: zero expands if any tie is free
            {
                unsigned long long tf = tm;
                while (tf) {
                    int l = __ffsll((long long)tf) - 1;
                    tf &= tf - 1;
                    int jp = __builtin_amdgcn_readlane(bestjp, l);
                    if ((jp >> 11) == 0) { freecol = jp & 0x7FF; break; }
                }
            }
            if (freecol) break;

            // 2) settle all matched ties at gmin
            while (tm) {
                int l = __ffsll((long long)tm) - 1;
                tm &= tm - 1;
                int jp = __builtin_amdgcn_readlane(bestjp, l);
                int jj = jp & 0x7FF, rr = jp >> 11;
                Frag F = issueLoads(rr);          // loads fly during marking
                if (lane == 0) dentry[jj] = gmin;
                int cc = jj - 1, lo = cc >> 4, kk = cc & 15;
                bool mine = (lane == lo);
#pragma unroll
                for (int k = 0; k < NSLOT; ++k)
                    if (k == kk && mine) { minv[k] = NANF; used |= (1u << k); }
                applyFrag(F, jj, gmin);
            }
        }
        if (freecol == 0) continue;

        // deferred dual updates (pre-augment pr)
        if (lane == 0) u_lds[i] += DT;
#pragma unroll
        for (int k = 0; k < NSLOT; ++k) {
            if ((used >> k) & 1u) {
                int j = lane * NSLOT + k + 1;
                float dd = DT - dentry[j];
                v[k] -= dd;
                u_lds[pr[k]] += dd;      // distinct rows: race-free
            }
        }
        __syncthreads();

        // augment along alternating path (register p via readlanes)
        int j0 = freecol;
        int aguard = 0;
        while (j0 != 0) {
            if (++aguard > N + 4) break;
            int cc = j0 - 1;
            int lo = cc >> 4, kk = cc & 15;
            int wloc = way[0];
#pragma unroll
            for (int k = 1; k < NSLOT; ++k) if (k == kk) wloc = way[k];
            int j1 = __builtin_amdgcn_readlane(wloc, lo);
            int np;
            if (j1 == 0) np = i;
            else {
                int c1 = j1 - 1;
                int lo1 = c1 >> 4, kk1 = c1 & 15;
                int ploc = pr[0];
#pragma unroll
                for (int k = 1; k < NSLOT; ++k) if (k == kk1) ploc = pr[k];
                np = __builtin_amdgcn_readlane(ploc, lo1);
            }
            bool mine = (lane == lo);
#pragma unroll
            for (int k = 0; k < NSLOT; ++k)
                if (k == kk) {
                    if (mine) { pr[k] = np; jpk[k] = (np << 11) | j0; }
                }
            if (lane == 0) rowm[np] = j0;
            j0 = j1;
        }
        __syncthreads();
    }

    // ---- total matched cost: exact fp32 from coordinates ----
    float sum = 0.0f;
#pragma unroll
    for (int k = 0; k < NSLOT; ++k) {
        int r = pr[k] > 0 ? pr[k] : 1;
        float4 qq = s1u[r];
        float dx = qq.x - x2[k], dy = qq.y - y2[k], dz = qq.z - z2[k];
        sum += sqrtf(dx * dx + dy * dy + dz * dz);
    }
#pragma unroll
    for (int off = 32; off >= 1; off >>= 1) sum += __shfl_xor(sum, off);
    if (lane == 0) atomicAdd(out, sum * (1.0f / ((float)N * (float)BATCH)));
}

extern "C" void kernel_launch(void* const* d_in, const int* in_sizes, int n_in,
                              void* d_out, int out_size, void* d_ws, size_t ws_size,
                              hipStream_t stream) {
    const float* S1 = (const float*)d_in[0];
    const float* S2 = (const float*)d_in[1];
    float* out = (float*)d_out;

    size_t needD = (size_t)BATCH * N * N * sizeof(__half);
    size_t needT = needD + (size_t)BATCH * N * (sizeof(float) + sizeof(int));

    emd_zero_kernel<<<1, 1, 0, stream>>>(out);

    if (ws_size >= needT) {
        __half* D = (__half*)d_ws;
        float* V = (float*)((char*)d_ws + needD);
        int*   I = (int*)(V + BATCH * N);
        emd_dist_kernel<<<BATCH * N, 256, 0, stream>>>(S1, S2, D);
        emd_colmin_kernel<<<BATCH * 4, 256, 0, stream>>>(D, V, I);
        emd_jv_kernel<true><<<BATCH, 64, 0, stream>>>(S1, S2, D, V, I, out);
    } else {
        emd_jv_kernel<false><<<BATCH, 64, 0, stream>>>(S1, S2, nullptr, nullptr, nullptr, out);
    }
}